// Round 3
// baseline (144.177 us; speedup 1.0000x reference)
//
#include <hip/hip_runtime.h>

// NPairCriterion on MI355X.
// batch: [B=131072, 128] f32; anchors/positives: [A=65536] i32; negatives: [A,16] i32.
// out: scalar f32 = mean_i log1p(sum_j exp(a_i·(n_ij - p_i))) + 0.005 * mean_b ||batch_b||.
// Stable LSE: log1p(sum exp x) = m + log(exp(-m) + sum exp(x-m)), m = max(0, max x).
//
// Structure: 16-lane groups own full D=128 dots (8 floats/lane via 2x float4,
// 4-step xor butterfly). 4 groups/wave process 4 negatives per round -> 5
// rounds per anchor (16 negs + a.p) = 24 DS ops/anchor vs 102 in the wave64
// butterfly version. L2-norm pass fused into the same kernel (hides under
// VALU-bound npair work).

#define WPB 4  // waves per block (256 threads)

__global__ __launch_bounds__(64) void zero_acc_kernel(double* acc) {
    if (threadIdx.x < 2) acc[threadIdx.x] = 0.0;
}

__global__ __launch_bounds__(256) void fused_kernel(
        const float* __restrict__ batch,
        const int* __restrict__ anchors,
        const int* __restrict__ positives,
        const int* __restrict__ negatives,
        double* __restrict__ acc,
        int A, int B)
{
    const int lane = threadIdx.x & 63;
    const int g    = lane >> 4;        // group 0..3
    const int sub  = lane & 15;        // lane within group
    const int wib  = threadIdx.x >> 6;
    const int nw   = gridDim.x * WPB;
    const int wid  = blockIdx.x * WPB + wib;
    const float4* b4 = (const float4*)batch;   // row stride = 32 float4

    // ---- npair loss: one anchor per wave-iteration ----
    float local = 0.f;
    for (int i = wid; i < A; i += nw) {
        const int ai = anchors[i];
        const int pi = positives[i];
        const float4* arow = b4 + (size_t)ai * 32;
        const float4* prow = b4 + (size_t)pi * 32;
        float4 a0 = arow[sub], a1 = arow[16 + sub];
        float4 p0 = prow[sub], p1 = prow[16 + sub];

        // a . p  (all 4 groups compute identically)
        float tap = a0.x*p0.x + a0.y*p0.y + a0.z*p0.z + a0.w*p0.w
                  + a1.x*p1.x + a1.y*p1.y + a1.z*p1.z + a1.w*p1.w;
#pragma unroll
        for (int off = 1; off < 16; off <<= 1) tap += __shfl_xor(tap, off, 64);

        float inner[4];
#pragma unroll
        for (int r = 0; r < 4; ++r) {
            const int idx = negatives[(size_t)i * 16 + r * 4 + g];
            const float4* nrow = b4 + (size_t)idx * 32;
            float4 n0 = nrow[sub], n1 = nrow[16 + sub];
            float t = a0.x*n0.x + a0.y*n0.y + a0.z*n0.z + a0.w*n0.w
                    + a1.x*n1.x + a1.y*n1.y + a1.z*n1.z + a1.w*n1.w;
#pragma unroll
            for (int off = 1; off < 16; off <<= 1) t += __shfl_xor(t, off, 64);
            inner[r] = t - tap;            // all lanes of group g hold it
        }

        // stable LSE over the 16 values (4 per group) + the implicit "+1"
        float m = fmaxf(fmaxf(inner[0], inner[1]), fmaxf(inner[2], inner[3]));
        m = fmaxf(m, __shfl_xor(m, 16, 64));
        m = fmaxf(m, __shfl_xor(m, 32, 64));
        m = fmaxf(m, 0.f);
        float s = __expf(inner[0] - m) + __expf(inner[1] - m)
                + __expf(inner[2] - m) + __expf(inner[3] - m);
        s += __shfl_xor(s, 16, 64);
        s += __shfl_xor(s, 32, 64);
        local += m + __logf(__expf(-m) + s);   // identical in all lanes
    }

    // ---- l2 term: 4 rows per wave-iteration ----
    float l2loc = 0.f;
    const int nquad = B >> 2;
    for (int q = wid; q < nquad; q += nw) {
        const int row = q * 4 + g;
        const float4* rrow = b4 + (size_t)row * 32;
        float4 v0 = rrow[sub], v1 = rrow[16 + sub];
        float ss = v0.x*v0.x + v0.y*v0.y + v0.z*v0.z + v0.w*v0.w
                 + v1.x*v1.x + v1.y*v1.y + v1.z*v1.z + v1.w*v1.w;
#pragma unroll
        for (int off = 1; off < 16; off <<= 1) ss += __shfl_xor(ss, off, 64);
        float t = sqrtf(ss);
        t += __shfl_xor(t, 16, 64);
        t += __shfl_xor(t, 32, 64);
        l2loc += t;                            // identical in all lanes
    }

    __shared__ float partN[WPB], partL[WPB];
    if (lane == 0) { partN[wib] = local; partL[wib] = l2loc; }
    __syncthreads();
    if (threadIdx.x == 0) {
        float tn = 0.f, tl = 0.f;
        for (int w = 0; w < WPB; ++w) { tn += partN[w]; tl += partL[w]; }
        atomicAdd(&acc[0], (double)tn);
        atomicAdd(&acc[1], (double)tl);
    }
}

__global__ __launch_bounds__(64) void finalize_kernel(
        const double* __restrict__ acc, float* __restrict__ out, int A, int B)
{
    if (threadIdx.x == 0) {
        double npair = acc[0] / (double)A;
        double l2    = 0.005 * (acc[1] / (double)B);
        out[0] = (float)(npair + l2);
    }
}

extern "C" void kernel_launch(void* const* d_in, const int* in_sizes, int n_in,
                              void* d_out, int out_size, void* d_ws, size_t ws_size,
                              hipStream_t stream) {
    const float* batch     = (const float*)d_in[0];
    const int*   anchors   = (const int*)d_in[1];
    const int*   positives = (const int*)d_in[2];
    const int*   negatives = (const int*)d_in[3];
    float*  out = (float*)d_out;
    double* acc = (double*)d_ws;

    const int A = in_sizes[1];          // 65536
    const int B = in_sizes[0] / 128;    // 131072

    hipLaunchKernelGGL(zero_acc_kernel, dim3(1), dim3(64), 0, stream, acc);
    hipLaunchKernelGGL(fused_kernel, dim3(4096), dim3(256), 0, stream,
                       batch, anchors, positives, negatives, acc, A, B);
    hipLaunchKernelGGL(finalize_kernel, dim3(1), dim3(64), 0, stream, acc, out, A, B);
}

// Round 4
// 139.343 us; speedup vs baseline: 1.0347x; 1.0347x over previous
//
#include <hip/hip_runtime.h>

// NPairCriterion on MI355X.
// batch: [B=131072, 128] f32; anchors/positives: [A=65536] i32; negatives: [A,16] i32.
// out: scalar f32 = mean_i log1p(sum_j exp(a_i·(n_ij - p_i))) + 0.005 * mean_b ||batch_b||.
// Stable LSE: log1p(sum exp x) = m + log(exp(-m) + sum exp(x-m)), m = max(0, max x).
//
// R3 lesson: latency-bound (VALUBusy 13%, HBM 29%, nothing saturated).
// Structure: ONE ANCHOR PER 16-LANE GROUP -> 4 independent gather/reduce
// pipelines per wave. Each group loads its own a,p rows (8 f32/lane), its 16
// negative indices (1/lane, shfl-broadcast) and 16 negative rows; LSE is a
// per-group in-register reduction over 16 values. ~39 independent VMEM loads
// issuable per wave-iteration.

#define WPB 4  // waves per block (256 threads)

__global__ __launch_bounds__(64) void zero_acc_kernel(double* acc) {
    if (threadIdx.x < 2) acc[threadIdx.x] = 0.0;
}

__device__ __forceinline__ float dot8(float4 a0, float4 a1, float4 b0, float4 b1) {
    return a0.x*b0.x + a0.y*b0.y + a0.z*b0.z + a0.w*b0.w
         + a1.x*b1.x + a1.y*b1.y + a1.z*b1.z + a1.w*b1.w;
}

__global__ __launch_bounds__(256) void fused_kernel(
        const float* __restrict__ batch,
        const int* __restrict__ anchors,
        const int* __restrict__ positives,
        const int* __restrict__ negatives,
        double* __restrict__ acc,
        int A, int B)
{
    const int lane = threadIdx.x & 63;
    const int g    = lane >> 4;        // group 0..3
    const int sub  = lane & 15;        // lane within group
    const int gbase = lane & 48;       // group's base lane for shfl broadcast
    const int wib  = threadIdx.x >> 6;
    const int nw   = gridDim.x * WPB;
    const int wid  = blockIdx.x * WPB + wib;
    const float4* b4 = (const float4*)batch;   // row stride = 32 float4

    // ---- npair loss: one anchor per GROUP per iteration ----
    float local = 0.f;   // per-group (replicated in 16 lanes)
    for (int base = wid * 4; base < A; base += nw * 4) {
        const int i  = base + g;
        const int ic = (i < A) ? i : (A - 1);

        const int ai = anchors[ic];
        const int pi = positives[ic];
        const int nidx = negatives[(size_t)ic * 16 + sub];  // lane sub holds neg index sub

        const float4* arow = b4 + (size_t)ai * 32;
        const float4* prow = b4 + (size_t)pi * 32;
        float4 a0 = arow[sub], a1 = arow[16 + sub];
        float4 p0 = prow[sub], p1 = prow[16 + sub];

        float tap = dot8(a0, a1, p0, p1);
#pragma unroll
        for (int off = 1; off < 16; off <<= 1) tap += __shfl_xor(tap, off, 64);

        float inner[16];
#pragma unroll
        for (int j = 0; j < 16; ++j) {
            const int idx = __shfl(nidx, gbase + j, 64);
            const float4* nrow = b4 + (size_t)idx * 32;
            float4 n0 = nrow[sub], n1 = nrow[16 + sub];
            float t = dot8(a0, a1, n0, n1);
#pragma unroll
            for (int off = 1; off < 16; off <<= 1) t += __shfl_xor(t, off, 64);
            inner[j] = t - tap;
        }

        // per-group stable LSE over 16 in-register values (+ implicit "+1")
        float m = 0.f;
#pragma unroll
        for (int j = 0; j < 16; ++j) m = fmaxf(m, inner[j]);
        float s = __expf(-m);
#pragma unroll
        for (int j = 0; j < 16; ++j) s += __expf(inner[j] - m);
        float v = m + __logf(s);
        if (i < A) local += v;
    }

    // ---- l2 term: one row per GROUP per iteration ----
    float l2loc = 0.f;   // per-group
    for (int base = wid * 4; base < B; base += nw * 4) {
        const int row = base + g;
        const int rc  = (row < B) ? row : (B - 1);
        const float4* rrow = b4 + (size_t)rc * 32;
        float4 v0 = rrow[sub], v1 = rrow[16 + sub];
        float ss = dot8(v0, v1, v0, v1);
#pragma unroll
        for (int off = 1; off < 16; off <<= 1) ss += __shfl_xor(ss, off, 64);
        if (row < B) l2loc += sqrtf(ss);
    }

    // cross-group sum: group values replicated per-sub-lane align across groups
    local += __shfl_xor(local, 16, 64);
    local += __shfl_xor(local, 32, 64);
    l2loc += __shfl_xor(l2loc, 16, 64);
    l2loc += __shfl_xor(l2loc, 32, 64);
    // now wave-uniform, but each group's 16 copies were identical -> value is
    // sum over 4 groups, replicated in all 64 lanes.

    __shared__ float partN[WPB], partL[WPB];
    if (lane == 0) { partN[wib] = local; partL[wib] = l2loc; }
    __syncthreads();
    if (threadIdx.x == 0) {
        float tn = 0.f, tl = 0.f;
        for (int w = 0; w < WPB; ++w) { tn += partN[w]; tl += partL[w]; }
        atomicAdd(&acc[0], (double)tn);
        atomicAdd(&acc[1], (double)tl);
    }
}

__global__ __launch_bounds__(64) void finalize_kernel(
        const double* __restrict__ acc, float* __restrict__ out, int A, int B)
{
    if (threadIdx.x == 0) {
        double npair = acc[0] / (double)A;
        double l2    = 0.005 * (acc[1] / (double)B);
        out[0] = (float)(npair + l2);
    }
}

extern "C" void kernel_launch(void* const* d_in, const int* in_sizes, int n_in,
                              void* d_out, int out_size, void* d_ws, size_t ws_size,
                              hipStream_t stream) {
    const float* batch     = (const float*)d_in[0];
    const int*   anchors   = (const int*)d_in[1];
    const int*   positives = (const int*)d_in[2];
    const int*   negatives = (const int*)d_in[3];
    float*  out = (float*)d_out;
    double* acc = (double*)d_ws;

    const int A = in_sizes[1];          // 65536
    const int B = in_sizes[0] / 128;    // 131072

    hipLaunchKernelGGL(zero_acc_kernel, dim3(1), dim3(64), 0, stream, acc);
    hipLaunchKernelGGL(fused_kernel, dim3(4096), dim3(256), 0, stream,
                       batch, anchors, positives, negatives, acc, A, B);
    hipLaunchKernelGGL(finalize_kernel, dim3(1), dim3(64), 0, stream, acc, out, A, B);
}

// Round 5
// 117.737 us; speedup vs baseline: 1.2246x; 1.1835x over previous
//
#include <hip/hip_runtime.h>

// NPairCriterion on MI355X.
// batch: [B=131072, 128] f32; anchors/positives: [A=65536] i32; negatives: [A,16] i32.
// out = mean_i log1p(sum_j exp(a_i·(n_ij - p_i))) + 0.005 * mean_b ||batch_b||.
// Stable LSE: log1p(sum exp x) = m + log(exp(-m) + sum exp(x-m)), m = max(0, max x).
//
// R4 lesson: time pinned at ~137us across 3 structurally different kernels while
// VALUBusy fell to 10% -> bound by L2-miss gather traffic (~310MB @ ~2.3TB/s).
// R5 move: gather from a bf16 copy of batch (halves miss bytes; 1 dwordx4 per
// row per lane). L2-norm fused into the conversion pass. f32 fallback if ws
// is too small.

#define WPB 4  // waves per block (256 threads)

__global__ __launch_bounds__(64) void zero_acc_kernel(double* acc) {
    if (threadIdx.x < 2) acc[threadIdx.x] = 0.0;
}

__device__ __forceinline__ float dot8(float4 a0, float4 a1, float4 b0, float4 b1) {
    return a0.x*b0.x + a0.y*b0.y + a0.z*b0.z + a0.w*b0.w
         + a1.x*b1.x + a1.y*b1.y + a1.z*b1.z + a1.w*b1.w;
}

__device__ __forceinline__ unsigned pack_bf16(float f0, float f1) {
    union { float f; unsigned u; } a, b;
    a.f = f0; b.f = f1;
    unsigned ua = (a.u + 0x7fffu + ((a.u >> 16) & 1u)) >> 16;   // RN-even
    unsigned ub = (b.u + 0x7fffu + ((b.u >> 16) & 1u)) >> 16;
    return ua | (ub << 16);
}

__device__ __forceinline__ void bf2f(unsigned u, float& lo, float& hi) {
    union { unsigned i; float f; } a, b;
    a.i = u << 16; b.i = u & 0xffff0000u;
    lo = a.f; hi = b.f;
}

__device__ __forceinline__ float dotbf(const float* af, uint4 u) {
    float lo, hi, s;
    bf2f(u.x, lo, hi); s  = af[0]*lo + af[1]*hi;
    bf2f(u.y, lo, hi); s += af[2]*lo + af[3]*hi;
    bf2f(u.z, lo, hi); s += af[4]*lo + af[5]*hi;
    bf2f(u.w, lo, hi); s += af[6]*lo + af[7]*hi;
    return s;
}

// ---- pass 1: f32 batch -> bf16 copy in ws, fused mean-||row|| accumulation ----
__global__ __launch_bounds__(256) void convert_norm_kernel(
        const float* __restrict__ batch, uint4* __restrict__ bb,
        double* __restrict__ acc, int B)
{
    const int lane = threadIdx.x & 63;
    const int g    = lane >> 4;
    const int sub  = lane & 15;
    const int wib  = threadIdx.x >> 6;
    const int nw   = gridDim.x * WPB;
    const int wid  = blockIdx.x * WPB + wib;
    const float4* b4 = (const float4*)batch;

    float l2loc = 0.f;
    for (int base = wid * 4; base < B; base += nw * 4) {
        const int row = base + g;
        if (row < B) {
            float4 v0 = b4[(size_t)row * 32 + sub * 2];
            float4 v1 = b4[(size_t)row * 32 + sub * 2 + 1];
            float ss = dot8(v0, v1, v0, v1);
#pragma unroll
            for (int off = 1; off < 16; off <<= 1) ss += __shfl_xor(ss, off, 64);
            uint4 o;
            o.x = pack_bf16(v0.x, v0.y); o.y = pack_bf16(v0.z, v0.w);
            o.z = pack_bf16(v1.x, v1.y); o.w = pack_bf16(v1.z, v1.w);
            bb[(size_t)row * 16 + sub] = o;
            if (sub == 0) l2loc += sqrtf(ss);
        }
    }
    // l2loc nonzero only at sub==0 lanes; full-wave sum
#pragma unroll
    for (int off = 32; off > 0; off >>= 1) l2loc += __shfl_xor(l2loc, off, 64);

    __shared__ float partL[WPB];
    if (lane == 0) partL[wib] = l2loc;
    __syncthreads();
    if (threadIdx.x == 0) {
        float t = 0.f;
        for (int w = 0; w < WPB; ++w) t += partL[w];
        atomicAdd(&acc[1], (double)t);
    }
}

// ---- pass 2: npair loss from bf16 rows; one anchor per 16-lane group ----
__global__ __launch_bounds__(256) void npair_bf16_kernel(
        const uint4* __restrict__ bb,
        const int* __restrict__ anchors,
        const int* __restrict__ positives,
        const int* __restrict__ negatives,
        double* __restrict__ acc, int A)
{
    const int lane  = threadIdx.x & 63;
    const int g     = lane >> 4;
    const int sub   = lane & 15;
    const int gbase = lane & 48;
    const int wib   = threadIdx.x >> 6;
    const int nw    = gridDim.x * WPB;
    const int wid   = blockIdx.x * WPB + wib;

    float local = 0.f;
    for (int base = wid * 4; base < A; base += nw * 4) {
        const int i  = base + g;
        const int ic = (i < A) ? i : (A - 1);

        const int ai = anchors[ic];
        const int pi = positives[ic];
        const int nidx = negatives[(size_t)ic * 16 + sub];

        uint4 ar = bb[(size_t)ai * 16 + sub];
        uint4 pr = bb[(size_t)pi * 16 + sub];

        // issue all 16 negative-row loads before any reduction (64 VGPR, static idx)
        uint4 nr[16];
#pragma unroll
        for (int j = 0; j < 16; ++j) {
            const int idx = __shfl(nidx, gbase + j, 64);
            nr[j] = bb[(size_t)idx * 16 + sub];
        }

        float af[8];
        bf2f(ar.x, af[0], af[1]); bf2f(ar.y, af[2], af[3]);
        bf2f(ar.z, af[4], af[5]); bf2f(ar.w, af[6], af[7]);

        float tap = dotbf(af, pr);
#pragma unroll
        for (int off = 1; off < 16; off <<= 1) tap += __shfl_xor(tap, off, 64);

        float inner[16];
#pragma unroll
        for (int j = 0; j < 16; ++j) {
            float t = dotbf(af, nr[j]);
#pragma unroll
            for (int off = 1; off < 16; off <<= 1) t += __shfl_xor(t, off, 64);
            inner[j] = t - tap;
        }

        float m = 0.f;
#pragma unroll
        for (int j = 0; j < 16; ++j) m = fmaxf(m, inner[j]);
        float s = __expf(-m);
#pragma unroll
        for (int j = 0; j < 16; ++j) s += __expf(inner[j] - m);
        if (i < A) local += m + __logf(s);
    }

    local += __shfl_xor(local, 16, 64);
    local += __shfl_xor(local, 32, 64);

    __shared__ float partN[WPB];
    if (lane == 0) partN[wib] = local;
    __syncthreads();
    if (threadIdx.x == 0) {
        float t = 0.f;
        for (int w = 0; w < WPB; ++w) t += partN[w];
        atomicAdd(&acc[0], (double)t);
    }
}

// ---- f32 fallback (R4 kernel): npair + l2 in one pass, if ws too small ----
__global__ __launch_bounds__(256) void fused_f32_kernel(
        const float* __restrict__ batch,
        const int* __restrict__ anchors,
        const int* __restrict__ positives,
        const int* __restrict__ negatives,
        double* __restrict__ acc, int A, int B)
{
    const int lane = threadIdx.x & 63;
    const int g    = lane >> 4;
    const int sub  = lane & 15;
    const int gbase = lane & 48;
    const int wib  = threadIdx.x >> 6;
    const int nw   = gridDim.x * WPB;
    const int wid  = blockIdx.x * WPB + wib;
    const float4* b4 = (const float4*)batch;

    float local = 0.f;
    for (int base = wid * 4; base < A; base += nw * 4) {
        const int i  = base + g;
        const int ic = (i < A) ? i : (A - 1);
        const int ai = anchors[ic];
        const int pi = positives[ic];
        const int nidx = negatives[(size_t)ic * 16 + sub];
        const float4* arow = b4 + (size_t)ai * 32;
        const float4* prow = b4 + (size_t)pi * 32;
        float4 a0 = arow[sub], a1 = arow[16 + sub];
        float4 p0 = prow[sub], p1 = prow[16 + sub];
        float tap = dot8(a0, a1, p0, p1);
#pragma unroll
        for (int off = 1; off < 16; off <<= 1) tap += __shfl_xor(tap, off, 64);
        float inner[16];
#pragma unroll
        for (int j = 0; j < 16; ++j) {
            const int idx = __shfl(nidx, gbase + j, 64);
            const float4* nrow = b4 + (size_t)idx * 32;
            float4 n0 = nrow[sub], n1 = nrow[16 + sub];
            float t = dot8(a0, a1, n0, n1);
#pragma unroll
            for (int off = 1; off < 16; off <<= 1) t += __shfl_xor(t, off, 64);
            inner[j] = t - tap;
        }
        float m = 0.f;
#pragma unroll
        for (int j = 0; j < 16; ++j) m = fmaxf(m, inner[j]);
        float s = __expf(-m);
#pragma unroll
        for (int j = 0; j < 16; ++j) s += __expf(inner[j] - m);
        if (i < A) local += m + __logf(s);
    }

    float l2loc = 0.f;
    for (int base = wid * 4; base < B; base += nw * 4) {
        const int row = base + g;
        if (row < B) {
            const float4* rrow = b4 + (size_t)row * 32;
            float4 v0 = rrow[sub], v1 = rrow[16 + sub];
            float ss = dot8(v0, v1, v0, v1);
#pragma unroll
            for (int off = 1; off < 16; off <<= 1) ss += __shfl_xor(ss, off, 64);
            if (sub == 0) l2loc += sqrtf(ss);
        }
    }

    local += __shfl_xor(local, 16, 64);
    local += __shfl_xor(local, 32, 64);
#pragma unroll
    for (int off = 32; off > 0; off >>= 1) l2loc += __shfl_xor(l2loc, off, 64);

    __shared__ float partN[WPB], partL[WPB];
    if (lane == 0) { partN[wib] = local; partL[wib] = l2loc; }
    __syncthreads();
    if (threadIdx.x == 0) {
        float tn = 0.f, tl = 0.f;
        for (int w = 0; w < WPB; ++w) { tn += partN[w]; tl += partL[w]; }
        atomicAdd(&acc[0], (double)tn);
        atomicAdd(&acc[1], (double)tl);
    }
}

__global__ __launch_bounds__(64) void finalize_kernel(
        const double* __restrict__ acc, float* __restrict__ out, int A, int B)
{
    if (threadIdx.x == 0) {
        double npair = acc[0] / (double)A;
        double l2    = 0.005 * (acc[1] / (double)B);
        out[0] = (float)(npair + l2);
    }
}

extern "C" void kernel_launch(void* const* d_in, const int* in_sizes, int n_in,
                              void* d_out, int out_size, void* d_ws, size_t ws_size,
                              hipStream_t stream) {
    const float* batch     = (const float*)d_in[0];
    const int*   anchors   = (const int*)d_in[1];
    const int*   positives = (const int*)d_in[2];
    const int*   negatives = (const int*)d_in[3];
    float*  out = (float*)d_out;
    double* acc = (double*)d_ws;

    const int A = in_sizes[1];          // 65536
    const int B = in_sizes[0] / 128;    // 131072

    const size_t need = (size_t)B * 128 * 2 + 64;
    hipLaunchKernelGGL(zero_acc_kernel, dim3(1), dim3(64), 0, stream, acc);

    if (ws_size >= need) {
        uint4* bb = (uint4*)((char*)d_ws + 64);
        hipLaunchKernelGGL(convert_norm_kernel, dim3(2048), dim3(256), 0, stream,
                           batch, bb, acc, B);
        hipLaunchKernelGGL(npair_bf16_kernel, dim3(4096), dim3(256), 0, stream,
                           bb, anchors, positives, negatives, acc, A);
    } else {
        hipLaunchKernelGGL(fused_f32_kernel, dim3(4096), dim3(256), 0, stream,
                           batch, anchors, positives, negatives, acc, A, B);
    }
    hipLaunchKernelGGL(finalize_kernel, dim3(1), dim3(64), 0, stream, acc, out, A, B);
}